// Round 7
// baseline (37.841 us; speedup 1.0000x reference)
//
#include <hip/hip_runtime.h>

#define BB 8
#define NN 256
#define DD 128
#define LN_EPS 1e-5f

// ---------------------------------------------------------------------------
// k_proj: hi = x @ w1[:D],  hjb = x @ w1[D:] + b1     (round-2 structure)
// grid 256 blocks (8 rows) x 512 threads: dp = tid&127 (output col),
// kg = tid>>7 (k-quarter). Row operand x via wave-uniform loads (s_load,
// SMEM pipe), weights via coalesced VMEM. Partials combined through LDS.
// ---------------------------------------------------------------------------
__global__ __launch_bounds__(512) void k_proj(const float* __restrict__ x,
                                              const float* __restrict__ w1,
                                              const float* __restrict__ b1,
                                              float* __restrict__ hi,
                                              float* __restrict__ hjb) {
    __shared__ float part_a[4][8][DD];
    __shared__ float part_b[4][8][DD];
    const int row0 = blockIdx.x * 8;
    const int tid  = threadIdx.x;
    const int dp   = tid & 127;
    const int kg   = tid >> 7;     // 0..3
    const int kb   = kg * 32;

    const float* __restrict__ wpa = w1 + dp;            // w1[k][dp], k in [0,128)
    const float* __restrict__ wpb = w1 + DD * DD + dp;  // w1[D+k][dp]

    float acc_a[8] = {}, acc_b[8] = {};
    #pragma unroll
    for (int k4 = 0; k4 < 8; ++k4) {
        const int k0 = kb + k4 * 4;
        float wa[4], wb[4];
        #pragma unroll
        for (int q = 0; q < 4; ++q) {
            wa[q] = wpa[(k0 + q) * DD];
            wb[q] = wpb[(k0 + q) * DD];
        }
        #pragma unroll
        for (int r = 0; r < 8; ++r) {
            const float* __restrict__ xr = x + (row0 + r) * DD + k0;  // uniform -> s_load
            #pragma unroll
            for (int q = 0; q < 4; ++q) {
                acc_a[r] = fmaf(xr[q], wa[q], acc_a[r]);
                acc_b[r] = fmaf(xr[q], wb[q], acc_b[r]);
            }
        }
    }
    #pragma unroll
    for (int r = 0; r < 8; ++r) {
        part_a[kg][r][dp] = acc_a[r];
        part_b[kg][r][dp] = acc_b[r];
    }
    __syncthreads();
    #pragma unroll
    for (int m = 0; m < 2; ++m) {
        int idx = tid + m * 512;            // 0..1023
        int r = idx >> 7, d = idx & 127;
        float sa = part_a[0][r][d] + part_a[1][r][d] + part_a[2][r][d] + part_a[3][r][d];
        float sb = part_b[0][r][d] + part_b[1][r][d] + part_b[2][r][d] + part_b[3][r][d];
        hi [(row0 + r) * DD + d] = sa;
        hjb[(row0 + r) * DD + d] = sb + b1[d];
    }
}

// ---------------------------------------------------------------------------
// k_pair: s[b,i,d] = sum_{j != i} relu(hi[b,i,d]+hjb[b,j,d]) * adj[b,i,j]
//         asum[b,i] = sum_{j != i} adj[b,i,j]
// grid 256 = (b:8)x(ig:32); 8 rows, FULL j range per block; 512 threads:
// dq = tid&31 (4 d's), row = (tid>>5)&7, jh = tid>>8 (j-half).
// Two j-halves proceed in parallel on separate hjs tiles and are combined
// in LDS at the end -> each output written exactly once, no atomics/memset.
// ---------------------------------------------------------------------------
__global__ __launch_bounds__(512) void k_pair(const float* __restrict__ adj,
                                              const float* __restrict__ hi,
                                              const float* __restrict__ hjb,
                                              float* __restrict__ s_out,
                                              float* __restrict__ asum) {
    __shared__ float a_t[8][NN];      // 8 KB masked adjacency rows
    __shared__ float hjs[2][64][DD];  // 64 KB, one tile per j-half
    float* const part = &hjs[0][0][0];  // [2][8][128] alias (used after hjs dead)

    const int bid = blockIdx.x;
    const int b   = bid >> 5;
    const int i0  = (bid & 31) * 8;
    const int tid = threadIdx.x;

    // stage masked adjacency: 8 x 256
    #pragma unroll
    for (int t = 0; t < 4; ++t) {
        int idx = tid + t * 512;            // 0..2047
        int il = idx >> 8, j = idx & 255;
        int ig = i0 + il;
        float av = adj[((size_t)b * NN + ig) * NN + j];
        a_t[il][j] = (j == ig) ? 0.f : av;
    }
    __syncthreads();

    // asum: one wave per row
    {
        int r = tid >> 6, l = tid & 63;
        float s = a_t[r][l] + a_t[r][l + 64] + a_t[r][l + 128] + a_t[r][l + 192];
        #pragma unroll
        for (int m = 32; m; m >>= 1) s += __shfl_xor(s, m);
        if (l == 0) asum[b * NN + i0 + r] = s;
    }

    const int dq  = tid & 31;        // d-quad
    const int row = (tid >> 5) & 7;  // 0..7
    const int jh  = tid >> 8;        // 0..1 (j-half)
    const float4 hi4 = *(const float4*)&hi[((size_t)b * NN + i0 + row) * DD + dq * 4];
    float4 acc = {0.f, 0.f, 0.f, 0.f};

    #pragma unroll
    for (int p = 0; p < 2; ++p) {
        __syncthreads();   // prev-tile reads done before overwrite
        // stage: hjs[0] <- rows [p*64, p*64+64), hjs[1] <- rows [128+p*64, ...)
        const float4* s0 = (const float4*)(hjb + ((size_t)b * NN + p * 64) * DD);
        const float4* s1 = (const float4*)(hjb + ((size_t)b * NN + 128 + p * 64) * DD);
        float4* d0 = (float4*)&hjs[0][0][0];
        float4* d1 = (float4*)&hjs[1][0][0];
        #pragma unroll
        for (int t = 0; t < 4; ++t) {
            d0[tid + t * 512] = s0[tid + t * 512];
            d1[tid + t * 512] = s1[tid + t * 512];
        }
        __syncthreads();
        const float* ar = &a_t[row][jh * 128 + p * 64];
        #pragma unroll 8
        for (int jj = 0; jj < 64; ++jj) {
            const float4 hv = *(const float4*)&hjs[jh][jj][dq * 4];
            const float a = ar[jj];
            acc.x = fmaf(fmaxf(hi4.x + hv.x, 0.f), a, acc.x);
            acc.y = fmaf(fmaxf(hi4.y + hv.y, 0.f), a, acc.y);
            acc.z = fmaf(fmaxf(hi4.z + hv.z, 0.f), a, acc.z);
            acc.w = fmaf(fmaxf(hi4.w + hv.w, 0.f), a, acc.w);
        }
    }
    __syncthreads();       // all hjs reads done before part alias writes
    *(float4*)&part[(jh * 8 + row) * DD + dq * 4] = acc;
    __syncthreads();
    // combine j-halves, coalesced write
    #pragma unroll
    for (int t = 0; t < 2; ++t) {
        int idx = tid + t * 512;            // 0..1023
        s_out[((size_t)b * NN + i0) * DD + idx] = part[idx] + part[1024 + idx];
    }
}

// ---------------------------------------------------------------------------
// k_tail: agg = s@w2 + b2*asum; u1 = relu(x@w3a + agg@w3b + b3);
//         upd = u1@w4 + b4; res = x + upd; out = LN(res)*g + beta
// (round-2 structure) grid 256 blocks (8 rows) x 512 threads; row operands
// via wave-uniform s_load, in-block operands via b128 LDS broadcast,
// weights via coalesced VMEM; 4-way k-partials combined in LDS.
// ---------------------------------------------------------------------------
__global__ __launch_bounds__(512) void k_tail(const float* __restrict__ x,
                                              const float* __restrict__ s_in,
                                              const float* __restrict__ asum,
                                              const float* __restrict__ w2,
                                              const float* __restrict__ b2,
                                              const float* __restrict__ w3,
                                              const float* __restrict__ b3,
                                              const float* __restrict__ w4,
                                              const float* __restrict__ b4,
                                              const float* __restrict__ g,
                                              const float* __restrict__ bet,
                                              float* __restrict__ out) {
    __shared__ float part[4][8][DD];   // 16KB
    __shared__ float aggs[8][DD];      // 4KB
    __shared__ float u1s[8][DD];       // 4KB
    __shared__ float resS[8][DD];      // 4KB
    __shared__ float asum_s[8];

    const int row0 = blockIdx.x * 8;
    const int tid  = threadIdx.x;
    const int dp   = tid & 127;
    const int kg   = tid >> 7;
    const int kb   = kg * 32;

    if (tid < 8) asum_s[tid] = asum[row0 + tid];

    // ---- stage A: agg = s@w2 (+ b2*asum at combine)
    {
        float acc[8] = {};
        const float* __restrict__ wp = w2 + dp;
        #pragma unroll
        for (int k4 = 0; k4 < 8; ++k4) {
            const int k0 = kb + k4 * 4;
            float wv[4];
            #pragma unroll
            for (int q = 0; q < 4; ++q) wv[q] = wp[(k0 + q) * DD];
            #pragma unroll
            for (int r = 0; r < 8; ++r) {
                const float* __restrict__ sr = s_in + (row0 + r) * DD + k0;  // uniform
                #pragma unroll
                for (int q = 0; q < 4; ++q) acc[r] = fmaf(sr[q], wv[q], acc[r]);
            }
        }
        #pragma unroll
        for (int r = 0; r < 8; ++r) part[kg][r][dp] = acc[r];
    }
    __syncthreads();
    #pragma unroll
    for (int m = 0; m < 2; ++m) {
        int idx = tid + m * 512;
        int r = idx >> 7, d = idx & 127;
        aggs[r][d] = part[0][r][d] + part[1][r][d] + part[2][r][d] + part[3][r][d]
                   + b2[d] * asum_s[r];
    }
    __syncthreads();

    // ---- stage B: u1 = relu(x@w3a + agg@w3b + b3)
    {
        float acc[8] = {};
        const float* __restrict__ wpa = w3 + dp;            // rows 0..127 (x part)
        const float* __restrict__ wpb = w3 + DD * DD + dp;  // rows 128..255 (agg part)
        #pragma unroll
        for (int k4 = 0; k4 < 8; ++k4) {
            const int k0 = kb + k4 * 4;
            float wa[4], wb[4];
            #pragma unroll
            for (int q = 0; q < 4; ++q) {
                wa[q] = wpa[(k0 + q) * DD];
                wb[q] = wpb[(k0 + q) * DD];
            }
            #pragma unroll
            for (int r = 0; r < 8; ++r) {
                const float4 av = *(const float4*)&aggs[r][k0];   // LDS b128 broadcast
                const float* __restrict__ xr = x + (row0 + r) * DD + k0;  // uniform
                acc[r] = fmaf(xr[0], wa[0], acc[r]);
                acc[r] = fmaf(xr[1], wa[1], acc[r]);
                acc[r] = fmaf(xr[2], wa[2], acc[r]);
                acc[r] = fmaf(xr[3], wa[3], acc[r]);
                acc[r] = fmaf(av.x, wb[0], acc[r]);
                acc[r] = fmaf(av.y, wb[1], acc[r]);
                acc[r] = fmaf(av.z, wb[2], acc[r]);
                acc[r] = fmaf(av.w, wb[3], acc[r]);
            }
        }
        #pragma unroll
        for (int r = 0; r < 8; ++r) part[kg][r][dp] = acc[r];
    }
    __syncthreads();
    #pragma unroll
    for (int m = 0; m < 2; ++m) {
        int idx = tid + m * 512;
        int r = idx >> 7, d = idx & 127;
        float v = part[0][r][d] + part[1][r][d] + part[2][r][d] + part[3][r][d] + b3[d];
        u1s[r][d] = fmaxf(v, 0.f);
    }
    __syncthreads();

    // ---- stage C: upd = u1@w4; res = x + upd + b4
    {
        float acc[8] = {};
        const float* __restrict__ wp = w4 + dp;
        #pragma unroll
        for (int k4 = 0; k4 < 8; ++k4) {
            const int k0 = kb + k4 * 4;
            float wv[4];
            #pragma unroll
            for (int q = 0; q < 4; ++q) wv[q] = wp[(k0 + q) * DD];
            #pragma unroll
            for (int r = 0; r < 8; ++r) {
                const float4 uv = *(const float4*)&u1s[r][k0];    // LDS b128 broadcast
                acc[r] = fmaf(uv.x, wv[0], acc[r]);
                acc[r] = fmaf(uv.y, wv[1], acc[r]);
                acc[r] = fmaf(uv.z, wv[2], acc[r]);
                acc[r] = fmaf(uv.w, wv[3], acc[r]);
            }
        }
        #pragma unroll
        for (int r = 0; r < 8; ++r) part[kg][r][dp] = acc[r];
    }
    __syncthreads();
    #pragma unroll
    for (int m = 0; m < 2; ++m) {
        int idx = tid + m * 512;
        int r = idx >> 7, d = idx & 127;
        resS[r][d] = x[(row0 + r) * DD + d]
                   + part[0][r][d] + part[1][r][d] + part[2][r][d] + part[3][r][d]
                   + b4[d];
    }
    __syncthreads();

    // ---- LayerNorm: one wave per row, 2 d's per lane
    {
        const int r = tid >> 6, l = tid & 63;
        const float2 v = *(const float2*)&resS[r][l * 2];
        float s1 = v.x + v.y;
        float s2 = v.x * v.x + v.y * v.y;
        #pragma unroll
        for (int m = 32; m; m >>= 1) {
            s1 += __shfl_xor(s1, m);
            s2 += __shfl_xor(s2, m);
        }
        const float mu = s1 * (1.f / DD);
        const float rs = rsqrtf(s2 * (1.f / DD) - mu * mu + LN_EPS);
        const int d = l * 2;
        const float2 gv = *(const float2*)&g[d];
        const float2 bv = *(const float2*)&bet[d];
        float2 o;
        o.x = (v.x - mu) * rs * gv.x + bv.x;
        o.y = (v.y - mu) * rs * gv.y + bv.y;
        *(float2*)&out[(row0 + r) * DD + d] = o;
    }
}

extern "C" void kernel_launch(void* const* d_in, const int* in_sizes, int n_in,
                              void* d_out, int out_size, void* d_ws, size_t ws_size,
                              hipStream_t stream) {
    (void)in_sizes; (void)n_in; (void)out_size; (void)ws_size;
    const float* x      = (const float*)d_in[0];
    const float* adj    = (const float*)d_in[1];
    const float* msg_w1 = (const float*)d_in[2];
    const float* msg_b1 = (const float*)d_in[3];
    const float* msg_w2 = (const float*)d_in[4];
    const float* msg_b2 = (const float*)d_in[5];
    const float* upd_w1 = (const float*)d_in[6];
    const float* upd_b1 = (const float*)d_in[7];
    const float* upd_w2 = (const float*)d_in[8];
    const float* upd_b2 = (const float*)d_in[9];
    const float* ln_g   = (const float*)d_in[10];
    const float* ln_b   = (const float*)d_in[11];
    float* out = (float*)d_out;

    const size_t BND = (size_t)BB * NN * DD;
    float* ws   = (float*)d_ws;
    float* s    = ws;                   // B*N*D
    float* asum = ws + BND;             // B*N
    float* hi   = asum + BB * NN;       // B*N*D
    float* hjb  = hi + BND;             // B*N*D

    k_proj<<<dim3(BB * NN / 8), dim3(512), 0, stream>>>(x, msg_w1, msg_b1, hi, hjb);
    k_pair<<<dim3(256), dim3(512), 0, stream>>>(adj, hi, hjb, s, asum);
    k_tail<<<dim3(BB * NN / 8), dim3(512), 0, stream>>>(x, s, asum, msg_w2, msg_b2,
                                                        upd_w1, upd_b1, upd_w2, upd_b2,
                                                        ln_g, ln_b, out);
}

// Round 8
// 37.697 us; speedup vs baseline: 1.0038x; 1.0038x over previous
//
#include <hip/hip_runtime.h>

#define BB 8
#define NN 256
#define DD 128
#define LN_EPS 1e-5f

__device__ __forceinline__ float rdlane(float v, int lane) {
    return __int_as_float(__builtin_amdgcn_readlane(__float_as_int(v), lane));
}

// ---------------------------------------------------------------------------
// k_proj: hi = x@w1[:D], hjb = x@w1[D:]+b1, xw3 = x@w3[:D]+b3
// 256 blocks (8 rows) x 512 threads. Wave w owns k-chunk [w*16, w*16+16);
// lane l holds x[row l>>4 (+4)][kb + (l&15)] in 2 VGPRs; activation values
// broadcast via v_readlane as SGPR FMA operands. Weights via coalesced VMEM.
// 3 passes (one per output) share the x registers; partials combined in LDS.
// ---------------------------------------------------------------------------
__global__ __launch_bounds__(512) void k_proj(const float* __restrict__ x,
                                              const float* __restrict__ w1,
                                              const float* __restrict__ b1,
                                              const float* __restrict__ w3,
                                              const float* __restrict__ b3,
                                              float* __restrict__ hi,
                                              float* __restrict__ hjb,
                                              float* __restrict__ xw3) {
    __shared__ float part[8192];   // [8][8][128] = 32 KB
    const int row0 = blockIdx.x * 8;
    const int tid  = threadIdx.x;
    const int lane = tid & 63;
    const int wv   = tid >> 6;     // 0..7
    const int kb   = wv * 16;

    const float va0 = x[(row0 + (lane >> 4)) * DD + kb + (lane & 15)];
    const float va1 = x[(row0 + (lane >> 4) + 4) * DD + kb + (lane & 15)];

    #pragma unroll
    for (int pass = 0; pass < 3; ++pass) {
        const float* __restrict__ W =
            (pass == 0) ? w1 : (pass == 1) ? (w1 + DD * DD) : w3;
        float w0[16], w1r[16];
        #pragma unroll
        for (int k = 0; k < 16; ++k) {
            w0[k]  = W[(kb + k) * DD + lane];
            w1r[k] = W[(kb + k) * DD + lane + 64];
        }
        #pragma unroll
        for (int r = 0; r < 8; ++r) {
            float a0 = 0.f, a1 = 0.f;
            #pragma unroll
            for (int k = 0; k < 16; ++k) {
                const float a = (r < 4) ? rdlane(va0, r * 16 + k)
                                        : rdlane(va1, (r - 4) * 16 + k);
                a0 = fmaf(a, w0[k], a0);
                a1 = fmaf(a, w1r[k], a1);
            }
            part[wv * 1024 + r * DD + lane]      = a0;
            part[wv * 1024 + r * DD + lane + 64] = a1;
        }
        __syncthreads();
        #pragma unroll
        for (int t = 0; t < 2; ++t) {
            int idx = tid + t * 512;           // 0..1023
            int r = idx >> 7, d = idx & 127;
            float s = 0.f;
            #pragma unroll
            for (int w = 0; w < 8; ++w) s += part[w * 1024 + r * DD + d];
            if (pass == 0)      hi [(row0 + r) * DD + d] = s;
            else if (pass == 1) hjb[(row0 + r) * DD + d] = s + b1[d];
            else                xw3[(row0 + r) * DD + d] = s + b3[d];
        }
        __syncthreads();
    }
}

// ---------------------------------------------------------------------------
// k_fused: pair (s, asum stay in LDS) + full tail. 256 blocks x 512 threads.
// Pair: a_tt[j][row] transposed (1 b128 = 4 rows' a), hjb staged in 64KB
// LDS halves; per thread 4 rows x 4 d per j -> 2 LDS b128 per 48 VALU.
// Tail: readlane-broadcast activations, VALU-bound stages.
// smem floats: [0,16384) hjs half (aliases aggs@0,u1s@1024,resS@2048,
// ssp@3072 after pair) | [16384,19456) a_tt[256][12] | [19456,27648) part
// | [27648..) asum
// ---------------------------------------------------------------------------
__global__ __launch_bounds__(512) void k_fused(const float* __restrict__ adj,
                                               const float* __restrict__ x,
                                               const float* __restrict__ hi,
                                               const float* __restrict__ hjb,
                                               const float* __restrict__ xw3,
                                               const float* __restrict__ w2,
                                               const float* __restrict__ b2,
                                               const float* __restrict__ w3,
                                               const float* __restrict__ w4,
                                               const float* __restrict__ b4,
                                               const float* __restrict__ g,
                                               const float* __restrict__ bet,
                                               float* __restrict__ out) {
    __shared__ float smem[27688];
    float* const hjs      = smem;            // [128][128] staged half
    float* const aggs     = smem;            // [8][128] alias (hjs dead)
    float* const u1s      = smem + 1024;     // [8][128]
    float* const resS     = smem + 2048;     // [8][128]
    float* const ssp      = smem + 3072;     // [8][128]
    float* const a_tt     = smem + 16384;    // [256][12]
    float* const part     = smem + 19456;    // [8][8][128]
    float* const asum_sub = smem + 27648;    // [8][4]
    float* const asum_s   = smem + 27680;    // [8]

    const int bid  = blockIdx.x;
    const int b    = bid >> 5;
    const int i0   = (bid & 31) * 8;
    const int tid  = threadIdx.x;
    const int lane = tid & 63;
    const int wv   = tid >> 6;   // 0..7

    // ---- stage transposed masked adjacency + asum partials
    #pragma unroll
    for (int t = 0; t < 4; ++t) {
        int idx = tid + t * 512;            // 0..2047
        int il = idx >> 8, j = idx & 255;   // il uniform per wave
        int ig = i0 + il;
        float av = adj[((size_t)b * NN + ig) * NN + j];
        av = (j == ig) ? 0.f : av;
        a_tt[j * 12 + il] = av;
        float s = av;
        #pragma unroll
        for (int m = 32; m; m >>= 1) s += __shfl_xor(s, m);
        if (lane == 0) asum_sub[il * 4 + ((idx >> 6) & 3)] = s;
    }

    // ---- pair: 4 rows x 4 d per thread, wave = j-split of 16 per half
    const int dq = lane & 31;
    const int rh = lane >> 5;
    const int r0 = rh * 4;
    float4 hi4[4];
    #pragma unroll
    for (int rr = 0; rr < 4; ++rr)
        hi4[rr] = *(const float4*)&hi[((size_t)b * NN + i0 + r0 + rr) * DD + dq * 4];
    float4 acc[4] = {{0,0,0,0},{0,0,0,0},{0,0,0,0},{0,0,0,0}};

    #pragma unroll
    for (int h = 0; h < 2; ++h) {
        __syncthreads();   // a_tt ready / prev-half reads done
        const float4* src = (const float4*)(hjb + ((size_t)b * NN + h * 128) * DD);
        float4* dst = (float4*)hjs;
        #pragma unroll
        for (int t = 0; t < 8; ++t) dst[tid + t * 512] = src[tid + t * 512];
        __syncthreads();
        const int jl0 = wv * 16;
        #pragma unroll
        for (int jj = 0; jj < 16; ++jj) {
            const int jl = jl0 + jj;
            const float4 hv = *(const float4*)&hjs[jl * DD + dq * 4];
            const float4 a4 = *(const float4*)&a_tt[(h * 128 + jl) * 12 + r0];
            const float aa[4] = {a4.x, a4.y, a4.z, a4.w};
            #pragma unroll
            for (int rr = 0; rr < 4; ++rr) {
                acc[rr].x = fmaf(fmaxf(hi4[rr].x + hv.x, 0.f), aa[rr], acc[rr].x);
                acc[rr].y = fmaf(fmaxf(hi4[rr].y + hv.y, 0.f), aa[rr], acc[rr].y);
                acc[rr].z = fmaf(fmaxf(hi4[rr].z + hv.z, 0.f), aa[rr], acc[rr].z);
                acc[rr].w = fmaf(fmaxf(hi4[rr].w + hv.w, 0.f), aa[rr], acc[rr].w);
            }
        }
    }
    #pragma unroll
    for (int rr = 0; rr < 4; ++rr)
        *(float4*)&part[wv * 1024 + (r0 + rr) * DD + dq * 4] = acc[rr];
    __syncthreads();

    if (tid < 8)
        asum_s[tid] = asum_sub[tid * 4] + asum_sub[tid * 4 + 1]
                    + asum_sub[tid * 4 + 2] + asum_sub[tid * 4 + 3];
    #pragma unroll
    for (int t = 0; t < 2; ++t) {
        int idx = tid + t * 512;
        float s = 0.f;
        #pragma unroll
        for (int w = 0; w < 8; ++w) s += part[w * 1024 + idx];
        ssp[idx] = s;
    }
    __syncthreads();

    // ---- tail: wave = k-chunk of 16; cols {lane, lane+64}; readlane acts
    const int kb = wv * 16;
    const int arow = lane >> 4, acol = kb + (lane & 15);

    // stage A: agg = ssp @ w2 (+ b2*asum at combine)
    {
        const float va0 = ssp[arow * DD + acol];
        const float va1 = ssp[(arow + 4) * DD + acol];
        float w0[16], w1r[16];
        #pragma unroll
        for (int k = 0; k < 16; ++k) {
            w0[k]  = w2[(kb + k) * DD + lane];
            w1r[k] = w2[(kb + k) * DD + lane + 64];
        }
        #pragma unroll
        for (int r = 0; r < 8; ++r) {
            float a0 = 0.f, a1 = 0.f;
            #pragma unroll
            for (int k = 0; k < 16; ++k) {
                const float a = (r < 4) ? rdlane(va0, r * 16 + k)
                                        : rdlane(va1, (r - 4) * 16 + k);
                a0 = fmaf(a, w0[k], a0);
                a1 = fmaf(a, w1r[k], a1);
            }
            part[wv * 1024 + r * DD + lane]      = a0;
            part[wv * 1024 + r * DD + lane + 64] = a1;
        }
    }
    __syncthreads();
    #pragma unroll
    for (int t = 0; t < 2; ++t) {
        int idx = tid + t * 512;
        int r = idx >> 7, d = idx & 127;
        float s = 0.f;
        #pragma unroll
        for (int w = 0; w < 8; ++w) s += part[w * 1024 + idx];
        aggs[idx] = s + b2[d] * asum_s[r];
    }
    __syncthreads();

    // stage B: u1 = relu(xw3 + agg @ w3b)
    {
        const float va0 = aggs[arow * DD + acol];
        const float va1 = aggs[(arow + 4) * DD + acol];
        const float* __restrict__ w3b = w3 + DD * DD;
        float w0[16], w1r[16];
        #pragma unroll
        for (int k = 0; k < 16; ++k) {
            w0[k]  = w3b[(kb + k) * DD + lane];
            w1r[k] = w3b[(kb + k) * DD + lane + 64];
        }
        #pragma unroll
        for (int r = 0; r < 8; ++r) {
            float a0 = 0.f, a1 = 0.f;
            #pragma unroll
            for (int k = 0; k < 16; ++k) {
                const float a = (r < 4) ? rdlane(va0, r * 16 + k)
                                        : rdlane(va1, (r - 4) * 16 + k);
                a0 = fmaf(a, w0[k], a0);
                a1 = fmaf(a, w1r[k], a1);
            }
            part[wv * 1024 + r * DD + lane]      = a0;
            part[wv * 1024 + r * DD + lane + 64] = a1;
        }
    }
    __syncthreads();
    #pragma unroll
    for (int t = 0; t < 2; ++t) {
        int idx = tid + t * 512;
        float s = xw3[((size_t)b * NN + i0) * DD + idx];
        #pragma unroll
        for (int w = 0; w < 8; ++w) s += part[w * 1024 + idx];
        u1s[idx] = fmaxf(s, 0.f);
    }
    __syncthreads();

    // stage C: res = x + u1 @ w4 + b4
    {
        const float va0 = u1s[arow * DD + acol];
        const float va1 = u1s[(arow + 4) * DD + acol];
        float w0[16], w1r[16];
        #pragma unroll
        for (int k = 0; k < 16; ++k) {
            w0[k]  = w4[(kb + k) * DD + lane];
            w1r[k] = w4[(kb + k) * DD + lane + 64];
        }
        #pragma unroll
        for (int r = 0; r < 8; ++r) {
            float a0 = 0.f, a1 = 0.f;
            #pragma unroll
            for (int k = 0; k < 16; ++k) {
                const float a = (r < 4) ? rdlane(va0, r * 16 + k)
                                        : rdlane(va1, (r - 4) * 16 + k);
                a0 = fmaf(a, w0[k], a0);
                a1 = fmaf(a, w1r[k], a1);
            }
            part[wv * 1024 + r * DD + lane]      = a0;
            part[wv * 1024 + r * DD + lane + 64] = a1;
        }
    }
    __syncthreads();
    #pragma unroll
    for (int t = 0; t < 2; ++t) {
        int idx = tid + t * 512;
        int d = idx & 127;
        float s = x[((size_t)b * NN + i0) * DD + idx] + b4[d];
        #pragma unroll
        for (int w = 0; w < 8; ++w) s += part[w * 1024 + idx];
        resS[idx] = s;
    }
    __syncthreads();

    // ---- LayerNorm: one wave per row
    {
        const int r = wv, l = lane;
        const float2 v = *(const float2*)&resS[r * DD + l * 2];
        float s1 = v.x + v.y;
        float s2 = v.x * v.x + v.y * v.y;
        #pragma unroll
        for (int m = 32; m; m >>= 1) {
            s1 += __shfl_xor(s1, m);
            s2 += __shfl_xor(s2, m);
        }
        const float mu = s1 * (1.f / DD);
        const float rs = rsqrtf(s2 * (1.f / DD) - mu * mu + LN_EPS);
        const int d = l * 2;
        const float2 gv = *(const float2*)&g[d];
        const float2 bv = *(const float2*)&bet[d];
        float2 o;
        o.x = (v.x - mu) * rs * gv.x + bv.x;
        o.y = (v.y - mu) * rs * gv.y + bv.y;
        *(float2*)&out[((size_t)b * NN + i0 + r) * DD + d] = o;
    }
}

extern "C" void kernel_launch(void* const* d_in, const int* in_sizes, int n_in,
                              void* d_out, int out_size, void* d_ws, size_t ws_size,
                              hipStream_t stream) {
    (void)in_sizes; (void)n_in; (void)out_size; (void)ws_size;
    const float* x      = (const float*)d_in[0];
    const float* adj    = (const float*)d_in[1];
    const float* msg_w1 = (const float*)d_in[2];
    const float* msg_b1 = (const float*)d_in[3];
    const float* msg_w2 = (const float*)d_in[4];
    const float* msg_b2 = (const float*)d_in[5];
    const float* upd_w1 = (const float*)d_in[6];
    const float* upd_b1 = (const float*)d_in[7];
    const float* upd_w2 = (const float*)d_in[8];
    const float* upd_b2 = (const float*)d_in[9];
    const float* ln_g   = (const float*)d_in[10];
    const float* ln_b   = (const float*)d_in[11];
    float* out = (float*)d_out;

    const size_t BND = (size_t)BB * NN * DD;
    float* ws  = (float*)d_ws;
    float* hi  = ws;            // B*N*D
    float* hjb = ws + BND;      // B*N*D
    float* xw3 = ws + 2 * BND;  // B*N*D

    k_proj<<<dim3(256), dim3(512), 0, stream>>>(x, msg_w1, msg_b1, upd_w1, upd_b1,
                                                hi, hjb, xw3);
    k_fused<<<dim3(256), dim3(512), 0, stream>>>(adj, x, hi, hjb, xw3,
                                                 msg_w2, msg_b2,
                                                 upd_w1, upd_w2, upd_b2,
                                                 ln_g, ln_b, out);
}

// Round 9
// 34.295 us; speedup vs baseline: 1.1034x; 1.0992x over previous
//
#include <hip/hip_runtime.h>

#define BB 8
#define NN 256
#define DD 128
#define LN_EPS 1e-5f

// ---------------------------------------------------------------------------
// k_proj: hi = x@w1[:D], hjb = x@w1[D:]+b1, xw3 = x@w3[:D]+b3
// grid 256 blocks (8 rows) x 512 threads: dp = tid&127, kg = tid>>7 (4-way
// k-split). xs staged in LDS; per (k4,r): one broadcast b128 feeds 12 FMAs
// (3 outputs). Weights via coalesced VMEM. Partials combined through LDS.
// ---------------------------------------------------------------------------
__global__ __launch_bounds__(512) void k_proj(const float* __restrict__ x,
                                              const float* __restrict__ w1,
                                              const float* __restrict__ b1,
                                              const float* __restrict__ w3,
                                              const float* __restrict__ b3,
                                              float* __restrict__ hi,
                                              float* __restrict__ hjb,
                                              float* __restrict__ xw3) {
    __shared__ float xs[8 * DD];     // 4 KB
    __shared__ float part[8192];     // 32 KB: two [4][8][128] halves
    const int row0 = blockIdx.x * 8;
    const int tid  = threadIdx.x;
    #pragma unroll
    for (int t = 0; t < 2; ++t) {
        int idx = tid + t * 512;
        xs[idx] = x[row0 * DD + idx];
    }
    __syncthreads();

    const int dp = tid & 127;
    const int kg = tid >> 7;
    const int kb = kg * 32;

    float aA[8] = {}, aB[8] = {}, aC[8] = {};
    #pragma unroll
    for (int k4 = 0; k4 < 8; ++k4) {
        const int k0 = kb + k4 * 4;
        float wa[4], wb[4], wc[4];
        #pragma unroll
        for (int q = 0; q < 4; ++q) {
            wa[q] = w1[(k0 + q) * DD + dp];
            wb[q] = w1[(DD + k0 + q) * DD + dp];
            wc[q] = w3[(k0 + q) * DD + dp];
        }
        #pragma unroll
        for (int r = 0; r < 8; ++r) {
            const float4 xv = *(const float4*)&xs[r * DD + k0];  // broadcast
            const float xq[4] = {xv.x, xv.y, xv.z, xv.w};
            #pragma unroll
            for (int q = 0; q < 4; ++q) {
                aA[r] = fmaf(xq[q], wa[q], aA[r]);
                aB[r] = fmaf(xq[q], wb[q], aB[r]);
                aC[r] = fmaf(xq[q], wc[q], aC[r]);
            }
        }
    }
    // combine A+B together, then C
    #pragma unroll
    for (int r = 0; r < 8; ++r) {
        part[kg * 1024 + r * DD + dp]        = aA[r];
        part[4096 + kg * 1024 + r * DD + dp] = aB[r];
    }
    __syncthreads();
    #pragma unroll
    for (int t = 0; t < 2; ++t) {
        int idx = tid + t * 512;
        int r = idx >> 7, d = idx & 127;
        float sa = 0.f, sb = 0.f;
        #pragma unroll
        for (int w = 0; w < 4; ++w) {
            sa += part[w * 1024 + r * DD + d];
            sb += part[4096 + w * 1024 + r * DD + d];
        }
        hi [(row0 + r) * DD + d] = sa;
        hjb[(row0 + r) * DD + d] = sb + b1[d];
    }
    __syncthreads();
    #pragma unroll
    for (int r = 0; r < 8; ++r) part[kg * 1024 + r * DD + dp] = aC[r];
    __syncthreads();
    #pragma unroll
    for (int t = 0; t < 2; ++t) {
        int idx = tid + t * 512;
        int r = idx >> 7, d = idx & 127;
        float sc = 0.f;
        #pragma unroll
        for (int w = 0; w < 4; ++w) sc += part[w * 1024 + r * DD + d];
        xw3[(row0 + r) * DD + d] = sc + b3[d];
    }
}

// ---------------------------------------------------------------------------
// k_fused: pair (a_tt transpose, double-buffered hjs tiles, reg-prefetch) +
// tail (2-col mapping, stage-B x-part hoisted to xw3). 256 blocks x 512 thr.
// smem floats: hjs0[0,8192) hjs1[8192,16384) part[16384,24576)
// a_tt[24576,27648) asum[27648,27688); tail aliases ssp@0 aggs@1024
// u1s@2048 resS@3072 (dead hjs region).
// ---------------------------------------------------------------------------
__global__ __launch_bounds__(512) void k_fused(const float* __restrict__ adj,
                                               const float* __restrict__ x,
                                               const float* __restrict__ hi,
                                               const float* __restrict__ hjb,
                                               const float* __restrict__ xw3,
                                               const float* __restrict__ w2,
                                               const float* __restrict__ b2,
                                               const float* __restrict__ w3,
                                               const float* __restrict__ w4,
                                               const float* __restrict__ b4,
                                               const float* __restrict__ g,
                                               const float* __restrict__ bet,
                                               float* __restrict__ out) {
    __shared__ float smem[27688];
    float* const hjs0     = smem;
    float* const hjs1     = smem + 8192;
    float* const part     = smem + 16384;
    float* const a_tt     = smem + 24576;   // [256][12]
    float* const asum_sub = smem + 27648;   // [8][4]
    float* const asum_s   = smem + 27680;   // [8]
    float* const ssp      = smem;           // [8][128] alias
    float* const aggs     = smem + 1024;
    float* const u1s      = smem + 2048;
    float* const resS     = smem + 3072;

    const int bid  = blockIdx.x;
    const int b    = bid >> 5;
    const int i0   = (bid & 31) * 8;
    const int tid  = threadIdx.x;
    const int lane = tid & 63;
    const int wv   = tid >> 6;   // 0..7

    // ---- adjacency transpose + asum partials (il is wave-uniform)
    #pragma unroll
    for (int t = 0; t < 4; ++t) {
        int idx = tid + t * 512;            // 0..2047
        int il = idx >> 8, j = idx & 255;
        int ig = i0 + il;
        float av = adj[((size_t)b * NN + ig) * NN + j];
        av = (j == ig) ? 0.f : av;
        a_tt[j * 12 + il] = av;
        float s = av;
        #pragma unroll
        for (int m = 32; m; m >>= 1) s += __shfl_xor(s, m);
        if (lane == 0) asum_sub[il * 4 + ((idx >> 6) & 3)] = s;
    }

    // ---- prologue: stage hjb tile 0 -> hjs0
    {
        const float4* src = (const float4*)(hjb + ((size_t)b * NN) * DD);
        float4* dst = (float4*)hjs0;
        #pragma unroll
        for (int q = 0; q < 4; ++q) dst[tid + q * 512] = src[tid + q * 512];
    }

    const int dq = lane & 31;
    const int r0 = (lane >> 5) * 4;
    float4 hi4[4];
    #pragma unroll
    for (int rr = 0; rr < 4; ++rr)
        hi4[rr] = *(const float4*)&hi[((size_t)b * NN + i0 + r0 + rr) * DD + dq * 4];
    float4 acc[4] = {{0,0,0,0},{0,0,0,0},{0,0,0,0},{0,0,0,0}};
    __syncthreads();

    // ---- pair: 4 tiles of 64 j; wave handles 8 j per tile; dbuf + prefetch
    #pragma unroll
    for (int t = 0; t < 4; ++t) {
        float* const cur = (t & 1) ? hjs1 : hjs0;
        float* const nxt = (t & 1) ? hjs0 : hjs1;
        float4 pf[4];
        if (t < 3) {
            const float4* src = (const float4*)(hjb + ((size_t)b * NN + (t + 1) * 64) * DD);
            #pragma unroll
            for (int q = 0; q < 4; ++q) pf[q] = src[tid + q * 512];
        }
        const int jbase = wv * 8;
        #pragma unroll
        for (int jj = 0; jj < 8; ++jj) {
            const int jl = jbase + jj;
            const float4 hv = *(const float4*)&cur[jl * DD + dq * 4];
            const float4 a4 = *(const float4*)&a_tt[(t * 64 + jl) * 12 + r0];
            const float aa[4] = {a4.x, a4.y, a4.z, a4.w};
            #pragma unroll
            for (int rr = 0; rr < 4; ++rr) {
                acc[rr].x = fmaf(fmaxf(hi4[rr].x + hv.x, 0.f), aa[rr], acc[rr].x);
                acc[rr].y = fmaf(fmaxf(hi4[rr].y + hv.y, 0.f), aa[rr], acc[rr].y);
                acc[rr].z = fmaf(fmaxf(hi4[rr].z + hv.z, 0.f), aa[rr], acc[rr].z);
                acc[rr].w = fmaf(fmaxf(hi4[rr].w + hv.w, 0.f), aa[rr], acc[rr].w);
            }
        }
        if (t < 3) {
            float4* dst = (float4*)nxt;
            #pragma unroll
            for (int q = 0; q < 4; ++q) dst[tid + q * 512] = pf[q];
        }
        __syncthreads();
    }

    // ---- partials -> ssp (8-way combine); finalize asum
    #pragma unroll
    for (int rr = 0; rr < 4; ++rr)
        *(float4*)&part[wv * 1024 + (r0 + rr) * DD + dq * 4] = acc[rr];
    __syncthreads();
    if (tid < 8)
        asum_s[tid] = asum_sub[tid * 4] + asum_sub[tid * 4 + 1]
                    + asum_sub[tid * 4 + 2] + asum_sub[tid * 4 + 3];
    #pragma unroll
    for (int t = 0; t < 2; ++t) {
        int idx = tid + t * 512;
        float s = 0.f;
        #pragma unroll
        for (int w = 0; w < 8; ++w) s += part[w * 1024 + idx];
        ssp[idx] = s;
    }
    __syncthreads();

    // ---- tail: 2 cols/thread (lane, lane+64), 8-way k-split (16 k per wave)
    const int kb = wv * 16;

    // stage A: agg = ssp @ w2 (+ b2*asum at combine)
    {
        float w0[16], w1r[16];
        #pragma unroll
        for (int k = 0; k < 16; ++k) {
            w0[k]  = w2[(kb + k) * DD + lane];
            w1r[k] = w2[(kb + k) * DD + lane + 64];
        }
        #pragma unroll
        for (int r = 0; r < 8; ++r) {
            float a0 = 0.f, a1 = 0.f;
            #pragma unroll
            for (int q = 0; q < 4; ++q) {
                const float4 sv = *(const float4*)&ssp[r * DD + kb + q * 4];  // broadcast
                a0 = fmaf(sv.x, w0[q*4+0], a0);  a1 = fmaf(sv.x, w1r[q*4+0], a1);
                a0 = fmaf(sv.y, w0[q*4+1], a0);  a1 = fmaf(sv.y, w1r[q*4+1], a1);
                a0 = fmaf(sv.z, w0[q*4+2], a0);  a1 = fmaf(sv.z, w1r[q*4+2], a1);
                a0 = fmaf(sv.w, w0[q*4+3], a0);  a1 = fmaf(sv.w, w1r[q*4+3], a1);
            }
            part[wv * 1024 + r * DD + lane]      = a0;
            part[wv * 1024 + r * DD + lane + 64] = a1;
        }
    }
    __syncthreads();
    #pragma unroll
    for (int t = 0; t < 2; ++t) {
        int idx = tid + t * 512;
        int r = idx >> 7, d = idx & 127;
        float s = 0.f;
        #pragma unroll
        for (int w = 0; w < 8; ++w) s += part[w * 1024 + idx];
        aggs[idx] = s + b2[d] * asum_s[r];
    }
    __syncthreads();

    // stage B: u1 = relu(xw3 + agg @ w3b)
    {
        const float* __restrict__ w3b = w3 + DD * DD;
        float w0[16], w1r[16];
        #pragma unroll
        for (int k = 0; k < 16; ++k) {
            w0[k]  = w3b[(kb + k) * DD + lane];
            w1r[k] = w3b[(kb + k) * DD + lane + 64];
        }
        #pragma unroll
        for (int r = 0; r < 8; ++r) {
            float a0 = 0.f, a1 = 0.f;
            #pragma unroll
            for (int q = 0; q < 4; ++q) {
                const float4 av = *(const float4*)&aggs[r * DD + kb + q * 4];
                a0 = fmaf(av.x, w0[q*4+0], a0);  a1 = fmaf(av.x, w1r[q*4+0], a1);
                a0 = fmaf(av.y, w0[q*4+1], a0);  a1 = fmaf(av.y, w1r[q*4+1], a1);
                a0 = fmaf(av.z, w0[q*4+2], a0);  a1 = fmaf(av.z, w1r[q*4+2], a1);
                a0 = fmaf(av.w, w0[q*4+3], a0);  a1 = fmaf(av.w, w1r[q*4+3], a1);
            }
            part[wv * 1024 + r * DD + lane]      = a0;
            part[wv * 1024 + r * DD + lane + 64] = a1;
        }
    }
    __syncthreads();
    #pragma unroll
    for (int t = 0; t < 2; ++t) {
        int idx = tid + t * 512;
        float s = xw3[((size_t)b * NN + i0) * DD + idx];
        #pragma unroll
        for (int w = 0; w < 8; ++w) s += part[w * 1024 + idx];
        u1s[idx] = fmaxf(s, 0.f);
    }
    __syncthreads();

    // stage C: res = x + u1 @ w4 + b4
    {
        float w0[16], w1r[16];
        #pragma unroll
        for (int k = 0; k < 16; ++k) {
            w0[k]  = w4[(kb + k) * DD + lane];
            w1r[k] = w4[(kb + k) * DD + lane + 64];
        }
        #pragma unroll
        for (int r = 0; r < 8; ++r) {
            float a0 = 0.f, a1 = 0.f;
            #pragma unroll
            for (int q = 0; q < 4; ++q) {
                const float4 uv = *(const float4*)&u1s[r * DD + kb + q * 4];
                a0 = fmaf(uv.x, w0[q*4+0], a0);  a1 = fmaf(uv.x, w1r[q*4+0], a1);
                a0 = fmaf(uv.y, w0[q*4+1], a0);  a1 = fmaf(uv.y, w1r[q*4+1], a1);
                a0 = fmaf(uv.z, w0[q*4+2], a0);  a1 = fmaf(uv.z, w1r[q*4+2], a1);
                a0 = fmaf(uv.w, w0[q*4+3], a0);  a1 = fmaf(uv.w, w1r[q*4+3], a1);
            }
            part[wv * 1024 + r * DD + lane]      = a0;
            part[wv * 1024 + r * DD + lane + 64] = a1;
        }
    }
    __syncthreads();
    #pragma unroll
    for (int t = 0; t < 2; ++t) {
        int idx = tid + t * 512;
        int d = idx & 127;
        float s = x[((size_t)b * NN + i0) * DD + idx] + b4[d];
        #pragma unroll
        for (int w = 0; w < 8; ++w) s += part[w * 1024 + idx];
        resS[idx] = s;
    }
    __syncthreads();

    // ---- LayerNorm: one wave per row
    {
        const int r = wv, l = lane;
        const float2 v = *(const float2*)&resS[r * DD + l * 2];
        float s1 = v.x + v.y;
        float s2 = v.x * v.x + v.y * v.y;
        #pragma unroll
        for (int m = 32; m; m >>= 1) {
            s1 += __shfl_xor(s1, m);
            s2 += __shfl_xor(s2, m);
        }
        const float mu = s1 * (1.f / DD);
        const float rs = rsqrtf(s2 * (1.f / DD) - mu * mu + LN_EPS);
        const int d = l * 2;
        const float2 gv = *(const float2*)&g[d];
        const float2 bv = *(const float2*)&bet[d];
        float2 o;
        o.x = (v.x - mu) * rs * gv.x + bv.x;
        o.y = (v.y - mu) * rs * gv.y + bv.y;
        *(float2*)&out[((size_t)b * NN + i0 + r) * DD + d] = o;
    }
}

extern "C" void kernel_launch(void* const* d_in, const int* in_sizes, int n_in,
                              void* d_out, int out_size, void* d_ws, size_t ws_size,
                              hipStream_t stream) {
    (void)in_sizes; (void)n_in; (void)out_size; (void)ws_size;
    const float* x      = (const float*)d_in[0];
    const float* adj    = (const float*)d_in[1];
    const float* msg_w1 = (const float*)d_in[2];
    const float* msg_b1 = (const float*)d_in[3];
    const float* msg_w2 = (const float*)d_in[4];
    const float* msg_b2 = (const float*)d_in[5];
    const float* upd_w1 = (const float*)d_in[6];
    const float* upd_b1 = (const float*)d_in[7];
    const float* upd_w2 = (const float*)d_in[8];
    const float* upd_b2 = (const float*)d_in[9];
    const float* ln_g   = (const float*)d_in[10];
    const float* ln_b   = (const float*)d_in[11];
    float* out = (float*)d_out;

    const size_t BND = (size_t)BB * NN * DD;
    float* ws  = (float*)d_ws;
    float* hi  = ws;            // B*N*D
    float* hjb = ws + BND;      // B*N*D
    float* xw3 = ws + 2 * BND;  // B*N*D

    k_proj<<<dim3(256), dim3(512), 0, stream>>>(x, msg_w1, msg_b1, upd_w1, upd_b1,
                                                hi, hjb, xw3);
    k_fused<<<dim3(256), dim3(512), 0, stream>>>(adj, x, hi, hjb, xw3,
                                                 msg_w2, msg_b2,
                                                 upd_w1, upd_w2, upd_b2,
                                                 ln_g, ln_b, out);
}